// Round 12
// baseline (228.833 us; speedup 1.0000x reference)
//
#include <hip/hip_runtime.h>

// ---------------------------------------------------------------------------
// SelfAttention (GQA + nonstandard RoPE), S=2048, HIDDEN=2048, 32 q-heads,
// 8 kv-heads, D=64.  Inputs/outputs FLOAT32; internal bf16 MFMA, fp32 accum.
// R23 = R22 (best 228.5us) with ONE change: prep's x-convert consolidated
// from 4096 blocks x 6KB (launch/drain-bound: 1 float4/thread) to 512
// blocks x 32KB (8 float4/thread, coalesced sweeps).  Budget forensics
// across R17-R22 show prep+gaps ~= 65-75us vs ~15us of actual traffic;
// the 4096-tiny-block x-convert is the mechanical suspect (G11).
// Everything else R22-exact: 128x64 GEMMs (gll16/vmcnt(6)/raw barriers,
// XCD swizzle), W_o transpose in QKV tail, flash in-block key-split with
// balance map + diagonal-only mask, f32-trig RoPE table.
// ---------------------------------------------------------------------------

typedef __bf16 bf16_t;
typedef __bf16 bf16x4 __attribute__((ext_vector_type(4)));
typedef __bf16 bf16x8 __attribute__((ext_vector_type(8)));
typedef float  f32x4  __attribute__((ext_vector_type(4)));
typedef short  s16x4  __attribute__((ext_vector_type(4)));

#define S_LEN   2048
#define HID     2048
#define NKV     8
#define NH      32
#define DHEAD   64
#define KVW     (NKV * DHEAD)   // 512

// ---- module-global scratch (rewritten fully each call) ---------------------
__device__ __align__(16) bf16_t g_xb [S_LEN * HID];     // x in bf16
__device__ __align__(16) bf16_t g_wTq[HID * HID];       // q_proj^T  [N][K]
__device__ __align__(16) bf16_t g_wTk[KVW * HID];       // k_proj^T
__device__ __align__(16) bf16_t g_wTv[KVW * HID];       // v_proj^T
__device__ __align__(16) bf16_t g_wTo[HID * HID];       // o_proj^T
__device__ __align__(16) bf16_t g_q [S_LEN * HID];      // roped Q
__device__ __align__(16) bf16_t g_k [S_LEN * KVW];      // roped K
__device__ __align__(16) bf16_t g_vT[KVW * S_LEN];      // V^T [d_total][S]
__device__ __align__(16) bf16_t g_om[S_LEN * HID];      // attn out (pre o_proj)
__device__ float g_ropeC[S_LEN * 32];
__device__ float g_ropeS[S_LEN * 32];

static __device__ inline s16x4 bc4(bf16x4 v) { s16x4 r; __builtin_memcpy(&r, &v, 8); return r; }

// async 16B global -> LDS.  lds base wave-uniform; data lands at base+lane*16.
__device__ __forceinline__ void gll16(void* lds, const void* g) {
    __builtin_amdgcn_global_load_lds(
        (const __attribute__((address_space(1))) void*)g,
        (__attribute__((address_space(3))) void*)lds,
        16, 0, 0);
}

// ---------------------------------------------------------------------------
// prep: (a) RoPE table (f32 angle + f32 trig; inv_freq dtype sniff),
// (b) x f32->bf16 (512 blocks x 8 float4/thread, was 4096 x 1 -- R23),
// (c) q/k/v weight transposes -> bf16 [C][R].  Grid 2304.
// ---------------------------------------------------------------------------
__global__ __launch_bounds__(256)
void prep_kernel(const float* __restrict__ x,
                 const float* __restrict__ qw, const float* __restrict__ kw,
                 const float* __restrict__ vw,
                 const void* __restrict__ invf_raw) {
    __shared__ float tile[64][65];
    int b = blockIdx.x, t = threadIdx.x;

    if (b < 256) {                               // RoPE table: 65536 entries
        int idx = b * 256 + t;
        int s = idx >> 5, j = idx & 31;
        float f;
        if (*(const unsigned*)invf_raw == 0x3F800000u) {
            f = ((const float*)invf_raw)[j];
        } else {
            unsigned u = ((unsigned)((const unsigned short*)invf_raw)[j]) << 16;
            __builtin_memcpy(&f, &u, 4);
        }
        float a32 = (float)s * f;                // f32 rounding (matches ref)
        g_ropeC[idx] = cosf(a32);
        g_ropeS[idx] = sinf(a32);
        return;
    }
    if (b < 768) {                               // x convert: 1M float4 total
        int base = (b - 256) * 2048;             // 512 blocks x 2048 f4 = 32KB
        #pragma unroll
        for (int j = 0; j < 8; ++j) {
            int idx = base + j * 256 + t;        // lane-consecutive sweeps
            float4 v = reinterpret_cast<const float4*>(x)[idx];
            bf16x4 o;
            o[0] = (bf16_t)v.x; o[1] = (bf16_t)v.y;
            o[2] = (bf16_t)v.z; o[3] = (bf16_t)v.w;
            *reinterpret_cast<bf16x4*>(&g_xb[(size_t)idx * 4]) = o;
        }
        return;
    }
    const float* in; bf16_t* outp; int R, C, tb;
    if (b < 1792)      { in = qw; outp = g_wTq; R = HID; C = HID; tb = b - 768; }
    else if (b < 2048) { in = kw; outp = g_wTk; R = HID; C = KVW; tb = b - 1792; }
    else               { in = vw; outp = g_wTv; R = HID; C = KVW; tb = b - 2048; }
    int xt = C >> 6;
    int c0 = (tb % xt) * 64, r0 = (tb / xt) * 64;

    int tx4 = t & 15, ty = t >> 4;               // float4 loads: 16x16 threads
    #pragma unroll
    for (int r = ty; r < 64; r += 16) {
        float4 v = *reinterpret_cast<const float4*>(
            &in[(size_t)(r0 + r) * C + c0 + tx4 * 4]);
        tile[r][tx4 * 4 + 0] = v.x;
        tile[r][tx4 * 4 + 1] = v.y;
        tile[r][tx4 * 4 + 2] = v.z;
        tile[r][tx4 * 4 + 3] = v.w;
    }
    __syncthreads();

    int cc = t & 63, j0 = t >> 6;                // output row n = c0+cc
    #pragma unroll
    for (int jj = 0; jj < 2; ++jj) {
        int j = j0 + jj * 4;                     // k-octet 0..7
        bf16x8 o8;
        #pragma unroll
        for (int i = 0; i < 8; ++i)
            o8[i] = (bf16_t)tile[8 * j + i][cc];
        *reinterpret_cast<bf16x8*>(&outp[(size_t)(c0 + cc) * R + r0 + 8 * j]) = o8;
    }
}

// ---------------------------------------------------------------------------
// Fused MFMA GEMM, 128x64 block tile, 4 waves each 32x64 (acc 2x4), BK=64,
// double-buffered gll16 staging, counted vmcnt(6) + raw-barrier pipeline,
// bijective XCD swizzle.  which=0: grid 1792 -- orig<768 QKV GEMM (nx 0-31
// Q+RoPE, 32-39 K+RoPE, 40-47 V transp); orig>=768 W_o TRANSPOSE (trailing,
// backfills drain; f32 tile reuses As).  which=1: O, f32 out, grid 512.
// ---------------------------------------------------------------------------
__global__ __launch_bounds__(256)
void gemm_fused_kernel(float* __restrict__ Cf, int which,
                       const float* __restrict__ ow) {
    __shared__ __align__(16) bf16_t As[2][128 * 64];    // 16 KB / buf
    __shared__ __align__(16) bf16_t Bs[2][64 * 64];     //  8 KB / buf

    int t    = threadIdx.x;

    if (which == 0 && blockIdx.x >= 768) {       // trailing W_o transpose
        float (*tile)[65] = reinterpret_cast<float (*)[65]>(&As[0][0]); // 16.6KB
        int tb = blockIdx.x - 768;               // 0..1023
        int c0 = (tb & 31) * 64, r0 = (tb >> 5) * 64;
        int tx4 = t & 15, ty = t >> 4;
        #pragma unroll
        for (int r = ty; r < 64; r += 16) {
            float4 v = *reinterpret_cast<const float4*>(
                &ow[(size_t)(r0 + r) * HID + c0 + tx4 * 4]);
            tile[r][tx4 * 4 + 0] = v.x;
            tile[r][tx4 * 4 + 1] = v.y;
            tile[r][tx4 * 4 + 2] = v.z;
            tile[r][tx4 * 4 + 3] = v.w;
        }
        __syncthreads();
        int cc = t & 63, j0 = t >> 6;
        #pragma unroll
        for (int jj = 0; jj < 2; ++jj) {
            int j = j0 + jj * 4;
            bf16x8 o8;
            #pragma unroll
            for (int i = 0; i < 8; ++i)
                o8[i] = (bf16_t)tile[8 * j + i][cc];
            *reinterpret_cast<bf16x8*>(&g_wTo[(size_t)(c0 + cc) * HID + r0 + 8 * j]) = o8;
        }
        return;
    }

    int lane = t & 63, wid = t >> 6;
    int quad = lane >> 4, l15 = lane & 15;

    int ntn  = (which == 1) ? 32 : 48;
    int nwg  = ntn * 16;
    int orig = blockIdx.x;
    int qq   = nwg >> 3;                         // nwg % 8 == 0 in both cases
    int wg   = (orig & 7) * qq + (orig >> 3);    // m204 bijective XCD swizzle
    int my   = wg / ntn, nx = wg - my * ntn;     // n-fastest: chunk shares A
    int m0   = my * 128;

    const bf16_t* A; const bf16_t* Bt; int n0;
    if (which == 1)      { A = g_om; Bt = g_wTo; n0 = nx * 64; }
    else {
        A = g_xb;
        if (nx < 32)      { Bt = g_wTq; n0 = nx * 64; }
        else if (nx < 40) { Bt = g_wTk; n0 = (nx - 32) * 64; }
        else              { Bt = g_wTv; n0 = (nx - 40) * 64; }
    }

    int crow = lane >> 3;                        // row within 8-row chunk
    int gseg = (lane & 7) ^ crow;                // swizzled 16B source octet
    int so   = l15 & 7;                          // read-side row swizzle key
    int wm   = wid * 32;                         // wave's M offset

    f32x4 acc[2][4];
    #pragma unroll
    for (int im = 0; im < 2; ++im)
        #pragma unroll
        for (int in = 0; in < 4; ++in)
            #pragma unroll
            for (int r = 0; r < 4; ++r) acc[im][in][r] = 0.f;

    // 6 gll16 per wave per stage: 4 A-chunks + 2 B-chunks (8 rows each).
    auto stage = [&](int buf, int kt) {
        #pragma unroll
        for (int c = 0; c < 4; ++c)
            gll16(&As[buf][(wid * 4 + c) * 512],
                  A  + (size_t)(m0 + (wid * 4 + c) * 8 + crow) * HID + kt + gseg * 8);
        #pragma unroll
        for (int c = 0; c < 2; ++c)
            gll16(&Bs[buf][(wid * 2 + c) * 512],
                  Bt + (size_t)(n0 + (wid * 2 + c) * 8 + crow) * HID + kt + gseg * 8);
    };

    stage(0, 0);                                  // preload buf 0 (6 in flight)

    for (int it = 0; it < 32; ++it) {
        int cur = it & 1;
        if (it + 1 < 32) {
            stage(cur ^ 1, (it + 1) * 64);        // +6 -> 12 in flight
            // wait ONLY for tile `it`'s 6 loads; next tile's stay in flight
            asm volatile("s_waitcnt vmcnt(6)" ::: "memory");
        } else {
            asm volatile("s_waitcnt vmcnt(0)" ::: "memory");
        }
        asm volatile("s_barrier" ::: "memory");   // tile-`it` data visible

        #pragma unroll
        for (int kh = 0; kh < 2; ++kh) {
            bf16x8 af[2], bfv[4];
            #pragma unroll
            for (int i = 0; i < 2; ++i)
                af[i]  = *reinterpret_cast<const bf16x8*>(
                    &As[cur][(wm + i * 16 + l15) * 64 + (((kh * 4 + quad) ^ so) * 8)]);
            #pragma unroll
            for (int i = 0; i < 4; ++i)
                bfv[i] = *reinterpret_cast<const bf16x8*>(
                    &Bs[cur][(i * 16 + l15) * 64 + (((kh * 4 + quad) ^ so) * 8)]);
            #pragma unroll
            for (int im = 0; im < 2; ++im)
                #pragma unroll
                for (int in = 0; in < 4; ++in)
                    acc[im][in] = __builtin_amdgcn_mfma_f32_16x16x32_bf16(
                        af[im], bfv[in], acc[im][in], 0, 0, 0);
        }

        asm volatile("s_barrier" ::: "memory");   // compute done; buf reusable
    }

    if (which == 1) {                            // O: f32 row-major
        #pragma unroll
        for (int im = 0; im < 2; ++im) {
            int rowb = m0 + wm + im * 16 + quad * 4;
            #pragma unroll
            for (int in = 0; in < 4; ++in) {
                int col = n0 + in * 16 + l15;
                #pragma unroll
                for (int r = 0; r < 4; ++r)
                    Cf[(size_t)(rowb + r) * HID + col] = acc[im][in][r];
            }
        }
    } else if (nx < 40) {                        // Q/K: RoPE epilogue -> bf16
        bf16_t* Cb; int N, colbase;
        if (nx < 32) { Cb = g_q; N = HID; colbase = nx * 64; }
        else         { Cb = g_k; N = KVW; colbase = (nx - 32) * 64; }
        // out[d] = x[d]*cos + x[d+32]*sin ; out[d+32] = x[d]*sin - x[d+32]*cos
        #pragma unroll
        for (int im = 0; im < 2; ++im) {
            #pragma unroll
            for (int r = 0; r < 4; ++r) {
                int row = m0 + wm + im * 16 + quad * 4 + r;
                #pragma unroll
                for (int in = 0; in < 2; ++in) {
                    int d = in * 16 + l15;                 // 0..31
                    float a  = acc[im][in][r];
                    float bb = acc[im][in + 2][r];
                    float cc = g_ropeC[row * 32 + d];
                    float ss = g_ropeS[row * 32 + d];
                    Cb[(size_t)row * N + colbase + d]      = (bf16_t)(a * cc + bb * ss);
                    Cb[(size_t)row * N + colbase + 32 + d] = (bf16_t)(a * ss - bb * cc);
                }
            }
        }
    } else {                                     // V: transposed store -> g_vT
        #pragma unroll
        for (int im = 0; im < 2; ++im) {
            int rowb = m0 + wm + im * 16 + quad * 4;
            #pragma unroll
            for (int in = 0; in < 4; ++in) {
                int col = (nx - 40) * 64 + in * 16 + l15;
                #pragma unroll
                for (int r = 0; r < 4; ++r)
                    g_vT[(size_t)col * S_LEN + (rowb + r)] = (bf16_t)acc[im][in][r];
            }
        }
    }
}

// ---------------------------------------------------------------------------
// Flash attention, IN-BLOCK key-split (causal, GQA, register-only P).
// 512 blocks = 8 kv-heads x 64 q-slots; 8 waves = 2 key-groups x 4 heads.
// slot->qb32 = slot<32 ? slot : 95-slot (per-CU balance, R20 +15us).
// Group g handles kt = g, g+2,... with gll16 XOR-octet staging, 2-buf,
// vmcnt(4), 2 barriers/tile.  Causal mask only on the DIAGONAL tile
// (kt==nkt-1); interior tiles provably unmasked.  Fixed-shift softmax
// p=exp(s-16): partials add; in-LDS combine (swizzled), bf16 g_om out.
// ---------------------------------------------------------------------------
__global__ __launch_bounds__(512)
void flash_part_kernel() {
    // [group][K=0/V=1][buf][64*64] ; per group 32 KB contiguous
    __shared__ __align__(16) bf16_t SM[2][2][2][64 * 64];

    int t    = threadIdx.x;
    int lane = t & 63, wid = t >> 6;          // wid 0..7
    int g    = wid >> 2;                      // key group 0/1
    int wh   = wid & 3;                       // head within kv-group
    int quad = lane >> 4, l15 = lane & 15;
    int bx   = blockIdx.x;
    int hk   = bx & 7;
    int slot = bx >> 3;                       // 0..63
    int qb32 = (slot < 32) ? slot : (95 - slot);   // pair-sum-to-63 balance
    int nkt  = (qb32 >> 1) + 1;               // 64-key tiles covering k <= q0+31
    int ng   = (nkt + 1) >> 1;                // iterations (uniform both groups)

    int head = hk * 4 + wh;
    int q0   = qb32 * 32;

    int crow = lane >> 3;                 // staging: row within 8-row chunk
    int gseg = (lane & 7) ^ crow;         // swizzled 16B source octet
    int so   = l15 & 7;                   // read-side swizzle key

    bf16x8 aq[2][2];
    #pragma unroll
    for (int mq = 0; mq < 2; ++mq) {
        const bf16_t* qp = g_q + (size_t)(q0 + mq * 16 + l15) * HID + head * 64 + quad * 8;
        aq[mq][0] = *reinterpret_cast<const bf16x8*>(qp);
        aq[mq][1] = *reinterpret_cast<const bf16x8*>(qp + 32);
        #pragma unroll
        for (int j = 0; j < 8; ++j) {
            aq[mq][0][j] = (bf16_t)((float)aq[mq][0][j] * 0.125f);  // exact
            aq[mq][1][j] = (bf16_t)((float)aq[mq][1][j] * 0.125f);
        }
    }

    bf16x4 ones4;
    #pragma unroll
    for (int j = 0; j < 4; ++j) ones4[j] = (bf16_t)1.0f;
    s16x4 ones_s = bc4(ones4);

    f32x4 oacc[2][4], liacc[2];
    #pragma unroll
    for (int mq = 0; mq < 2; ++mq) {
        #pragma unroll
        for (int r = 0; r < 4; ++r) liacc[mq][r] = 0.f;
        #pragma unroll
        for (int dt = 0; dt < 4; ++dt)
            #pragma unroll
            for (int r = 0; r < 4; ++r) oacc[mq][dt][r] = 0.f;
    }

    int qcol[2] = { q0 + l15, q0 + 16 + l15 };

    // 4 gll16 per wave per tile: 2 K-chunks + 2 V-chunks (8 rows each),
    // into this group's own buffers.
    auto stageKV = [&](int buf, int k0) {
        #pragma unroll
        for (int c = 0; c < 2; ++c) {
            int ch = wh * 2 + c;                          // chunk 0..7
            gll16(&SM[g][0][buf][ch * 512],
                  g_k  + (size_t)(k0 + ch * 8 + crow) * KVW + hk * 64 + gseg * 8);
            gll16(&SM[g][1][buf][ch * 512],
                  g_vT + (size_t)(hk * 64 + ch * 8 + crow) * S_LEN + k0 + gseg * 8);
        }
    };

    if (g < nkt) stageKV(0, g * 64);      // preload first tile of this group

    for (int i = 0; i < ng; ++i) {
        int cur  = i & 1;
        int kt   = 2 * i + g;
        bool live = (kt < nkt);
        int ktn  = kt + 2;
        bool stage_next = (i + 1 < ng) && (ktn < nkt);
        if (stage_next) {
            stageKV(cur ^ 1, ktn * 64);                    // +4 -> 8 in flight
            asm volatile("s_waitcnt vmcnt(4)" ::: "memory");   // tile kt landed
        } else {
            asm volatile("s_waitcnt vmcnt(0)" ::: "memory");
        }
        asm volatile("s_barrier" ::: "memory");

        if (live) {
            int k0 = kt * 64;
            // K fragments: row mk*16+l15, octet quad / 4+quad, XOR-swizzled
            bf16x8 ak[4][2];
            #pragma unroll
            for (int mk = 0; mk < 4; ++mk) {
                int row = mk * 16 + l15;
                ak[mk][0] = *reinterpret_cast<const bf16x8*>(&SM[g][0][cur][row * 64 + ((quad ^ so) * 8)]);
                ak[mk][1] = *reinterpret_cast<const bf16x8*>(&SM[g][0][cur][row * 64 + (((4 + quad) ^ so) * 8)]);
            }

            f32x4 sacc[4][2];
            #pragma unroll
            for (int mk = 0; mk < 4; ++mk)
                #pragma unroll
                for (int mq = 0; mq < 2; ++mq) {
                    f32x4 s;
                    #pragma unroll
                    for (int r = 0; r < 4; ++r) s[r] = 0.f;
                    s = __builtin_amdgcn_mfma_f32_16x16x32_bf16(ak[mk][0], aq[mq][0], s, 0, 0, 0);
                    s = __builtin_amdgcn_mfma_f32_16x16x32_bf16(ak[mk][1], aq[mq][1], s, 0, 0, 0);
                    sacc[mk][mq] = s;
                }

            s16x4 pas[4][2];
            if (kt == nkt - 1) {                 // diagonal tile: masked
                #pragma unroll
                for (int mk = 0; mk < 4; ++mk)
                    #pragma unroll
                    for (int mq = 0; mq < 2; ++mq) {
                        bf16x4 pa;
                        #pragma unroll
                        for (int r = 0; r < 4; ++r) {
                            int kk = k0 + mk * 16 + quad * 4 + r;
                            pa[r] = (bf16_t)((kk <= qcol[mq]) ? __expf(sacc[mk][mq][r] - 16.0f) : 0.0f);
                        }
                        pas[mk][mq] = bc4(pa);
                    }
            } else {                             // interior tile: all k < q0
                #pragma unroll
                for (int mk = 0; mk < 4; ++mk)
                    #pragma unroll
                    for (int mq = 0; mq < 2; ++mq) {
                        bf16x4 pa;
                        #pragma unroll
                        for (int r = 0; r < 4; ++r)
                            pa[r] = (bf16_t)__expf(sacc[mk][mq][r] - 16.0f);
                        pas[mk][mq] = bc4(pa);
                    }
            }

            #pragma unroll
            for (int mk = 0; mk < 4; ++mk) {
                #pragma unroll
                for (int dt = 0; dt < 4; ++dt) {
                    // V fragment: row dt*16+l15, cols mk*16+quad*4 (8B in octet)
                    int rv = dt * 16 + l15;
                    int vb = rv * 64 + (((mk * 2 + (quad >> 1)) ^ so) * 8) + (quad & 1) * 4;
                    bf16x4 bv = *reinterpret_cast<const bf16x4*>(&SM[g][1][cur][vb]);
                    s16x4 bvs = bc4(bv);
                    #pragma unroll
                    for (int mq = 0; mq < 2; ++mq)
                        oacc[mq][dt] = __builtin_amdgcn_mfma_f32_16x16x16bf16_1k(pas[mk][mq], bvs, oacc[mq][dt], 0, 0, 0);
                }
                #pragma unroll
                for (int mq = 0; mq < 2; ++mq)
                    liacc[mq] = __builtin_amdgcn_mfma_f32_16x16x16bf16_1k(pas[mk][mq], ones_s, liacc[mq], 0, 0, 0);
            }
        }

        asm volatile("s_barrier" ::: "memory");   // compute done; buf reusable
    }

    // -------- in-LDS combine: group 1 -> its freed staging area -------------
    float* pO = reinterpret_cast<float*>(&SM[1][0][0][0]);   // 32 KB
    float* pl = reinterpret_cast<float*>(&SM[0][0][0][0]);   // 512 B used
    if (g == 1) {
        #pragma unroll
        for (int mq = 0; mq < 2; ++mq)
            #pragma unroll
            for (int r = 0; r < 4; ++r) {
                int row = mq * 16 + quad * 4 + r;            // 0..31
                int sw  = ((row >> 2) & 3) << 3;
                #pragma unroll
                for (int dt = 0; dt < 4; ++dt)
                    pO[(wh * 32 + row) * 64 + ((dt * 16 + l15) ^ sw)] = oacc[mq][dt][r];
                if (l15 == 0) pl[wh * 32 + row] = liacc[mq][r];
            }
    }
    asm volatile("s_waitcnt lgkmcnt(0)" ::: "memory");
    asm volatile("s_barrier" ::: "memory");
    if (g == 0) {
        #pragma unroll
        for (int mq = 0; mq < 2; ++mq)
            #pragma unroll
            for (int r = 0; r < 4; ++r) {
                int row = mq * 16 + quad * 4 + r;            // 0..31
                int sw  = ((row >> 2) & 3) << 3;
                float l = liacc[mq][r] + pl[wh * 32 + row];
                float inv = 1.0f / l;
                #pragma unroll
                for (int dt = 0; dt < 4; ++dt) {
                    float o = oacc[mq][dt][r] + pO[(wh * 32 + row) * 64 + ((dt * 16 + l15) ^ sw)];
                    g_om[(size_t)(q0 + row) * HID + head * 64 + dt * 16 + l15] = (bf16_t)(o * inv);
                }
            }
    }
}

// ---------------------------------------------------------------------------
// Launch: 4 dispatches.
// ---------------------------------------------------------------------------
extern "C" void kernel_launch(void* const* d_in, const int* in_sizes, int n_in,
                              void* d_out, int out_size, void* d_ws, size_t ws_size,
                              hipStream_t stream) {
    const float* x    = (const float*)d_in[0];
    const float* qpW  = (const float*)d_in[1];
    const float* kpW  = (const float*)d_in[2];
    const float* vpW  = (const float*)d_in[3];
    const float* opW  = (const float*)d_in[4];
    const void*  invf = d_in[5];
    float* out = (float*)d_out;

    prep_kernel<<<2304, 256, 0, stream>>>(x, qpW, kpW, vpW, invf);     // rope+x+qkv-w
    gemm_fused_kernel<<<1792, 256, 0, stream>>>(nullptr, 0, opW);      // QKV + W_o^T
    flash_part_kernel<<<512, 512, 0, stream>>>();                      // 8kv x 64slot
    gemm_fused_kernel<<<512, 256, 0, stream>>>(out, 1, nullptr);       // O
}

// Round 13
// 224.091 us; speedup vs baseline: 1.0212x; 1.0212x over previous
//
#include <hip/hip_runtime.h>

// ---------------------------------------------------------------------------
// SelfAttention (GQA + nonstandard RoPE), S=2048, HIDDEN=2048, 32 q-heads,
// 8 kv-heads, D=64.  Inputs/outputs FLOAT32; internal bf16 MFMA, fp32 accum.
// R24 = R23 (228.8us) with ONE change: GEMM block->tile partition reshaped
// to SQUARE per-XCD regions for L2 residency.  All blocks of an XCD are
// co-resident, so the region SHAPE sets the concurrent L2 working set:
//   QKV old 2my x 48nx = A 1MB + B 12MB = 13MB  (L2 = 4MB -> B thrash)
//   QKV new 8my x 12nx = A 4MB + B  3MB =  7MB
//   O   new 8my x  8nx = A 4MB + B  2MB =  6MB
// Predicted: QKV FETCH 64->~45MB, O FETCH ~55->~38MB; dur -3..-6us each.
// Pre-committed: if FETCH drops but dur doesn't, staging ceiling is L2-path
// throughput (structural plateau).  Everything else R23-exact.
// ---------------------------------------------------------------------------

typedef __bf16 bf16_t;
typedef __bf16 bf16x4 __attribute__((ext_vector_type(4)));
typedef __bf16 bf16x8 __attribute__((ext_vector_type(8)));
typedef float  f32x4  __attribute__((ext_vector_type(4)));
typedef short  s16x4  __attribute__((ext_vector_type(4)));

#define S_LEN   2048
#define HID     2048
#define NKV     8
#define NH      32
#define DHEAD   64
#define KVW     (NKV * DHEAD)   // 512

// ---- module-global scratch (rewritten fully each call) ---------------------
__device__ __align__(16) bf16_t g_xb [S_LEN * HID];     // x in bf16
__device__ __align__(16) bf16_t g_wTq[HID * HID];       // q_proj^T  [N][K]
__device__ __align__(16) bf16_t g_wTk[KVW * HID];       // k_proj^T
__device__ __align__(16) bf16_t g_wTv[KVW * HID];       // v_proj^T
__device__ __align__(16) bf16_t g_wTo[HID * HID];       // o_proj^T
__device__ __align__(16) bf16_t g_q [S_LEN * HID];      // roped Q
__device__ __align__(16) bf16_t g_k [S_LEN * KVW];      // roped K
__device__ __align__(16) bf16_t g_vT[KVW * S_LEN];      // V^T [d_total][S]
__device__ __align__(16) bf16_t g_om[S_LEN * HID];      // attn out (pre o_proj)
__device__ float g_ropeC[S_LEN * 32];
__device__ float g_ropeS[S_LEN * 32];

static __device__ inline s16x4 bc4(bf16x4 v) { s16x4 r; __builtin_memcpy(&r, &v, 8); return r; }

// async 16B global -> LDS.  lds base wave-uniform; data lands at base+lane*16.
__device__ __forceinline__ void gll16(void* lds, const void* g) {
    __builtin_amdgcn_global_load_lds(
        (const __attribute__((address_space(1))) void*)g,
        (__attribute__((address_space(3))) void*)lds,
        16, 0, 0);
}

// ---------------------------------------------------------------------------
// prep: (a) RoPE table (f32 angle + f32 trig; inv_freq dtype sniff),
// (b) x f32->bf16 (512 blocks x 8 float4/thread),
// (c) q/k/v weight transposes -> bf16 [C][R].  Grid 2304.
// ---------------------------------------------------------------------------
__global__ __launch_bounds__(256)
void prep_kernel(const float* __restrict__ x,
                 const float* __restrict__ qw, const float* __restrict__ kw,
                 const float* __restrict__ vw,
                 const void* __restrict__ invf_raw) {
    __shared__ float tile[64][65];
    int b = blockIdx.x, t = threadIdx.x;

    if (b < 256) {                               // RoPE table: 65536 entries
        int idx = b * 256 + t;
        int s = idx >> 5, j = idx & 31;
        float f;
        if (*(const unsigned*)invf_raw == 0x3F800000u) {
            f = ((const float*)invf_raw)[j];
        } else {
            unsigned u = ((unsigned)((const unsigned short*)invf_raw)[j]) << 16;
            __builtin_memcpy(&f, &u, 4);
        }
        float a32 = (float)s * f;                // f32 rounding (matches ref)
        g_ropeC[idx] = cosf(a32);
        g_ropeS[idx] = sinf(a32);
        return;
    }
    if (b < 768) {                               // x convert: 1M float4 total
        int base = (b - 256) * 2048;             // 512 blocks x 2048 f4 = 32KB
        #pragma unroll
        for (int j = 0; j < 8; ++j) {
            int idx = base + j * 256 + t;        // lane-consecutive sweeps
            float4 v = reinterpret_cast<const float4*>(x)[idx];
            bf16x4 o;
            o[0] = (bf16_t)v.x; o[1] = (bf16_t)v.y;
            o[2] = (bf16_t)v.z; o[3] = (bf16_t)v.w;
            *reinterpret_cast<bf16x4*>(&g_xb[(size_t)idx * 4]) = o;
        }
        return;
    }
    const float* in; bf16_t* outp; int R, C, tb;
    if (b < 1792)      { in = qw; outp = g_wTq; R = HID; C = HID; tb = b - 768; }
    else if (b < 2048) { in = kw; outp = g_wTk; R = HID; C = KVW; tb = b - 1792; }
    else               { in = vw; outp = g_wTv; R = HID; C = KVW; tb = b - 2048; }
    int xt = C >> 6;
    int c0 = (tb % xt) * 64, r0 = (tb / xt) * 64;

    int tx4 = t & 15, ty = t >> 4;               // float4 loads: 16x16 threads
    #pragma unroll
    for (int r = ty; r < 64; r += 16) {
        float4 v = *reinterpret_cast<const float4*>(
            &in[(size_t)(r0 + r) * C + c0 + tx4 * 4]);
        tile[r][tx4 * 4 + 0] = v.x;
        tile[r][tx4 * 4 + 1] = v.y;
        tile[r][tx4 * 4 + 2] = v.z;
        tile[r][tx4 * 4 + 3] = v.w;
    }
    __syncthreads();

    int cc = t & 63, j0 = t >> 6;                // output row n = c0+cc
    #pragma unroll
    for (int jj = 0; jj < 2; ++jj) {
        int j = j0 + jj * 4;                     // k-octet 0..7
        bf16x8 o8;
        #pragma unroll
        for (int i = 0; i < 8; ++i)
            o8[i] = (bf16_t)tile[8 * j + i][cc];
        *reinterpret_cast<bf16x8*>(&outp[(size_t)(c0 + cc) * R + r0 + 8 * j]) = o8;
    }
}

// ---------------------------------------------------------------------------
// Fused MFMA GEMM, 128x64 block tile, 4 waves each 32x64 (acc 2x4), BK=64,
// double-buffered gll16 staging, counted vmcnt(6) + raw-barrier pipeline.
// R24 partition: square per-XCD regions (L2 working-set fit):
//   which=0 QKV: XCD k covers my in [(k&1)*8, +8), nx in [(k>>1)*12, +12).
//   which=1 O:   XCD k covers my in [(k&1)*8, +8), nx in [(k>>1)*8,  +8).
// which=0 grid 1792: orig<768 QKV GEMM (nx 0-31 Q+RoPE, 32-39 K+RoPE,
// 40-47 V transp); orig>=768 W_o TRANSPOSE.  which=1: O, f32 out, grid 512.
// ---------------------------------------------------------------------------
__global__ __launch_bounds__(256)
void gemm_fused_kernel(float* __restrict__ Cf, int which,
                       const float* __restrict__ ow) {
    __shared__ __align__(16) bf16_t As[2][128 * 64];    // 16 KB / buf
    __shared__ __align__(16) bf16_t Bs[2][64 * 64];     //  8 KB / buf

    int t    = threadIdx.x;

    if (which == 0 && blockIdx.x >= 768) {       // trailing W_o transpose
        float (*tile)[65] = reinterpret_cast<float (*)[65]>(&As[0][0]); // 16.6KB
        int tb = blockIdx.x - 768;               // 0..1023
        int c0 = (tb & 31) * 64, r0 = (tb >> 5) * 64;
        int tx4 = t & 15, ty = t >> 4;
        #pragma unroll
        for (int r = ty; r < 64; r += 16) {
            float4 v = *reinterpret_cast<const float4*>(
                &ow[(size_t)(r0 + r) * HID + c0 + tx4 * 4]);
            tile[r][tx4 * 4 + 0] = v.x;
            tile[r][tx4 * 4 + 1] = v.y;
            tile[r][tx4 * 4 + 2] = v.z;
            tile[r][tx4 * 4 + 3] = v.w;
        }
        __syncthreads();
        int cc = t & 63, j0 = t >> 6;
        #pragma unroll
        for (int jj = 0; jj < 2; ++jj) {
            int j = j0 + jj * 4;
            bf16x8 o8;
            #pragma unroll
            for (int i = 0; i < 8; ++i)
                o8[i] = (bf16_t)tile[8 * j + i][cc];
            *reinterpret_cast<bf16x8*>(&g_wTo[(size_t)(c0 + cc) * HID + r0 + 8 * j]) = o8;
        }
        return;
    }

    int lane = t & 63, wid = t >> 6;
    int quad = lane >> 4, l15 = lane & 15;

    // --- square per-XCD region partition (R24) ---
    int orig  = blockIdx.x;
    int xcd   = orig & 7;
    int local = orig >> 3;                       // 0..95 (QKV) / 0..63 (O)
    int my    = ((xcd & 1) << 3) + (local & 7);  // 8 my rows per region
    int nx;
    if (which == 1) nx = ((xcd >> 1) << 3) + (local >> 3);   // 8 nx per region
    else            nx = (xcd >> 1) * 12 + (local >> 3);     // 12 nx per region
    int m0 = my * 128;

    const bf16_t* A; const bf16_t* Bt; int n0;
    if (which == 1)      { A = g_om; Bt = g_wTo; n0 = nx * 64; }
    else {
        A = g_xb;
        if (nx < 32)      { Bt = g_wTq; n0 = nx * 64; }
        else if (nx < 40) { Bt = g_wTk; n0 = (nx - 32) * 64; }
        else              { Bt = g_wTv; n0 = (nx - 40) * 64; }
    }

    int crow = lane >> 3;                        // row within 8-row chunk
    int gseg = (lane & 7) ^ crow;                // swizzled 16B source octet
    int so   = l15 & 7;                          // read-side row swizzle key
    int wm   = wid * 32;                         // wave's M offset

    f32x4 acc[2][4];
    #pragma unroll
    for (int im = 0; im < 2; ++im)
        #pragma unroll
        for (int in = 0; in < 4; ++in)
            #pragma unroll
            for (int r = 0; r < 4; ++r) acc[im][in][r] = 0.f;

    // 6 gll16 per wave per stage: 4 A-chunks + 2 B-chunks (8 rows each).
    auto stage = [&](int buf, int kt) {
        #pragma unroll
        for (int c = 0; c < 4; ++c)
            gll16(&As[buf][(wid * 4 + c) * 512],
                  A  + (size_t)(m0 + (wid * 4 + c) * 8 + crow) * HID + kt + gseg * 8);
        #pragma unroll
        for (int c = 0; c < 2; ++c)
            gll16(&Bs[buf][(wid * 2 + c) * 512],
                  Bt + (size_t)(n0 + (wid * 2 + c) * 8 + crow) * HID + kt + gseg * 8);
    };

    stage(0, 0);                                  // preload buf 0 (6 in flight)

    for (int it = 0; it < 32; ++it) {
        int cur = it & 1;
        if (it + 1 < 32) {
            stage(cur ^ 1, (it + 1) * 64);        // +6 -> 12 in flight
            // wait ONLY for tile `it`'s 6 loads; next tile's stay in flight
            asm volatile("s_waitcnt vmcnt(6)" ::: "memory");
        } else {
            asm volatile("s_waitcnt vmcnt(0)" ::: "memory");
        }
        asm volatile("s_barrier" ::: "memory");   // tile-`it` data visible

        #pragma unroll
        for (int kh = 0; kh < 2; ++kh) {
            bf16x8 af[2], bfv[4];
            #pragma unroll
            for (int i = 0; i < 2; ++i)
                af[i]  = *reinterpret_cast<const bf16x8*>(
                    &As[cur][(wm + i * 16 + l15) * 64 + (((kh * 4 + quad) ^ so) * 8)]);
            #pragma unroll
            for (int i = 0; i < 4; ++i)
                bfv[i] = *reinterpret_cast<const bf16x8*>(
                    &Bs[cur][(i * 16 + l15) * 64 + (((kh * 4 + quad) ^ so) * 8)]);
            #pragma unroll
            for (int im = 0; im < 2; ++im)
                #pragma unroll
                for (int in = 0; in < 4; ++in)
                    acc[im][in] = __builtin_amdgcn_mfma_f32_16x16x32_bf16(
                        af[im], bfv[in], acc[im][in], 0, 0, 0);
        }

        asm volatile("s_barrier" ::: "memory");   // compute done; buf reusable
    }

    if (which == 1) {                            // O: f32 row-major
        #pragma unroll
        for (int im = 0; im < 2; ++im) {
            int rowb = m0 + wm + im * 16 + quad * 4;
            #pragma unroll
            for (int in = 0; in < 4; ++in) {
                int col = n0 + in * 16 + l15;
                #pragma unroll
                for (int r = 0; r < 4; ++r)
                    Cf[(size_t)(rowb + r) * HID + col] = acc[im][in][r];
            }
        }
    } else if (nx < 40) {                        // Q/K: RoPE epilogue -> bf16
        bf16_t* Cb; int N, colbase;
        if (nx < 32) { Cb = g_q; N = HID; colbase = nx * 64; }
        else         { Cb = g_k; N = KVW; colbase = (nx - 32) * 64; }
        // out[d] = x[d]*cos + x[d+32]*sin ; out[d+32] = x[d]*sin - x[d+32]*cos
        #pragma unroll
        for (int im = 0; im < 2; ++im) {
            #pragma unroll
            for (int r = 0; r < 4; ++r) {
                int row = m0 + wm + im * 16 + quad * 4 + r;
                #pragma unroll
                for (int in = 0; in < 2; ++in) {
                    int d = in * 16 + l15;                 // 0..31
                    float a  = acc[im][in][r];
                    float bb = acc[im][in + 2][r];
                    float cc = g_ropeC[row * 32 + d];
                    float ss = g_ropeS[row * 32 + d];
                    Cb[(size_t)row * N + colbase + d]      = (bf16_t)(a * cc + bb * ss);
                    Cb[(size_t)row * N + colbase + 32 + d] = (bf16_t)(a * ss - bb * cc);
                }
            }
        }
    } else {                                     // V: transposed store -> g_vT
        #pragma unroll
        for (int im = 0; im < 2; ++im) {
            int rowb = m0 + wm + im * 16 + quad * 4;
            #pragma unroll
            for (int in = 0; in < 4; ++in) {
                int col = (nx - 40) * 64 + in * 16 + l15;
                #pragma unroll
                for (int r = 0; r < 4; ++r)
                    g_vT[(size_t)col * S_LEN + (rowb + r)] = (bf16_t)acc[im][in][r];
            }
        }
    }
}

// ---------------------------------------------------------------------------
// Flash attention, IN-BLOCK key-split (causal, GQA, register-only P).
// 512 blocks = 8 kv-heads x 64 q-slots; 8 waves = 2 key-groups x 4 heads.
// slot->qb32 = slot<32 ? slot : 95-slot (per-CU balance, R20 +15us).
// Group g handles kt = g, g+2,... with gll16 XOR-octet staging, 2-buf,
// vmcnt(4), 2 barriers/tile.  Causal mask only on the DIAGONAL tile
// (kt==nkt-1); interior tiles provably unmasked.  Fixed-shift softmax
// p=exp(s-16): partials add; in-LDS combine (swizzled), bf16 g_om out.
// ---------------------------------------------------------------------------
__global__ __launch_bounds__(512)
void flash_part_kernel() {
    // [group][K=0/V=1][buf][64*64] ; per group 32 KB contiguous
    __shared__ __align__(16) bf16_t SM[2][2][2][64 * 64];

    int t    = threadIdx.x;
    int lane = t & 63, wid = t >> 6;          // wid 0..7
    int g    = wid >> 2;                      // key group 0/1
    int wh   = wid & 3;                       // head within kv-group
    int quad = lane >> 4, l15 = lane & 15;
    int bx   = blockIdx.x;
    int hk   = bx & 7;
    int slot = bx >> 3;                       // 0..63
    int qb32 = (slot < 32) ? slot : (95 - slot);   // pair-sum-to-63 balance
    int nkt  = (qb32 >> 1) + 1;               // 64-key tiles covering k <= q0+31
    int ng   = (nkt + 1) >> 1;                // iterations (uniform both groups)

    int head = hk * 4 + wh;
    int q0   = qb32 * 32;

    int crow = lane >> 3;                 // staging: row within 8-row chunk
    int gseg = (lane & 7) ^ crow;         // swizzled 16B source octet
    int so   = l15 & 7;                   // read-side swizzle key

    bf16x8 aq[2][2];
    #pragma unroll
    for (int mq = 0; mq < 2; ++mq) {
        const bf16_t* qp = g_q + (size_t)(q0 + mq * 16 + l15) * HID + head * 64 + quad * 8;
        aq[mq][0] = *reinterpret_cast<const bf16x8*>(qp);
        aq[mq][1] = *reinterpret_cast<const bf16x8*>(qp + 32);
        #pragma unroll
        for (int j = 0; j < 8; ++j) {
            aq[mq][0][j] = (bf16_t)((float)aq[mq][0][j] * 0.125f);  // exact
            aq[mq][1][j] = (bf16_t)((float)aq[mq][1][j] * 0.125f);
        }
    }

    bf16x4 ones4;
    #pragma unroll
    for (int j = 0; j < 4; ++j) ones4[j] = (bf16_t)1.0f;
    s16x4 ones_s = bc4(ones4);

    f32x4 oacc[2][4], liacc[2];
    #pragma unroll
    for (int mq = 0; mq < 2; ++mq) {
        #pragma unroll
        for (int r = 0; r < 4; ++r) liacc[mq][r] = 0.f;
        #pragma unroll
        for (int dt = 0; dt < 4; ++dt)
            #pragma unroll
            for (int r = 0; r < 4; ++r) oacc[mq][dt][r] = 0.f;
    }

    int qcol[2] = { q0 + l15, q0 + 16 + l15 };

    // 4 gll16 per wave per tile: 2 K-chunks + 2 V-chunks (8 rows each),
    // into this group's own buffers.
    auto stageKV = [&](int buf, int k0) {
        #pragma unroll
        for (int c = 0; c < 2; ++c) {
            int ch = wh * 2 + c;                          // chunk 0..7
            gll16(&SM[g][0][buf][ch * 512],
                  g_k  + (size_t)(k0 + ch * 8 + crow) * KVW + hk * 64 + gseg * 8);
            gll16(&SM[g][1][buf][ch * 512],
                  g_vT + (size_t)(hk * 64 + ch * 8 + crow) * S_LEN + k0 + gseg * 8);
        }
    };

    if (g < nkt) stageKV(0, g * 64);      // preload first tile of this group

    for (int i = 0; i < ng; ++i) {
        int cur  = i & 1;
        int kt   = 2 * i + g;
        bool live = (kt < nkt);
        int ktn  = kt + 2;
        bool stage_next = (i + 1 < ng) && (ktn < nkt);
        if (stage_next) {
            stageKV(cur ^ 1, ktn * 64);                    // +4 -> 8 in flight
            asm volatile("s_waitcnt vmcnt(4)" ::: "memory");   // tile kt landed
        } else {
            asm volatile("s_waitcnt vmcnt(0)" ::: "memory");
        }
        asm volatile("s_barrier" ::: "memory");

        if (live) {
            int k0 = kt * 64;
            // K fragments: row mk*16+l15, octet quad / 4+quad, XOR-swizzled
            bf16x8 ak[4][2];
            #pragma unroll
            for (int mk = 0; mk < 4; ++mk) {
                int row = mk * 16 + l15;
                ak[mk][0] = *reinterpret_cast<const bf16x8*>(&SM[g][0][cur][row * 64 + ((quad ^ so) * 8)]);
                ak[mk][1] = *reinterpret_cast<const bf16x8*>(&SM[g][0][cur][row * 64 + (((4 + quad) ^ so) * 8)]);
            }

            f32x4 sacc[4][2];
            #pragma unroll
            for (int mk = 0; mk < 4; ++mk)
                #pragma unroll
                for (int mq = 0; mq < 2; ++mq) {
                    f32x4 s;
                    #pragma unroll
                    for (int r = 0; r < 4; ++r) s[r] = 0.f;
                    s = __builtin_amdgcn_mfma_f32_16x16x32_bf16(ak[mk][0], aq[mq][0], s, 0, 0, 0);
                    s = __builtin_amdgcn_mfma_f32_16x16x32_bf16(ak[mk][1], aq[mq][1], s, 0, 0, 0);
                    sacc[mk][mq] = s;
                }

            s16x4 pas[4][2];
            if (kt == nkt - 1) {                 // diagonal tile: masked
                #pragma unroll
                for (int mk = 0; mk < 4; ++mk)
                    #pragma unroll
                    for (int mq = 0; mq < 2; ++mq) {
                        bf16x4 pa;
                        #pragma unroll
                        for (int r = 0; r < 4; ++r) {
                            int kk = k0 + mk * 16 + quad * 4 + r;
                            pa[r] = (bf16_t)((kk <= qcol[mq]) ? __expf(sacc[mk][mq][r] - 16.0f) : 0.0f);
                        }
                        pas[mk][mq] = bc4(pa);
                    }
            } else {                             // interior tile: all k < q0
                #pragma unroll
                for (int mk = 0; mk < 4; ++mk)
                    #pragma unroll
                    for (int mq = 0; mq < 2; ++mq) {
                        bf16x4 pa;
                        #pragma unroll
                        for (int r = 0; r < 4; ++r)
                            pa[r] = (bf16_t)__expf(sacc[mk][mq][r] - 16.0f);
                        pas[mk][mq] = bc4(pa);
                    }
            }

            #pragma unroll
            for (int mk = 0; mk < 4; ++mk) {
                #pragma unroll
                for (int dt = 0; dt < 4; ++dt) {
                    // V fragment: row dt*16+l15, cols mk*16+quad*4 (8B in octet)
                    int rv = dt * 16 + l15;
                    int vb = rv * 64 + (((mk * 2 + (quad >> 1)) ^ so) * 8) + (quad & 1) * 4;
                    bf16x4 bv = *reinterpret_cast<const bf16x4*>(&SM[g][1][cur][vb]);
                    s16x4 bvs = bc4(bv);
                    #pragma unroll
                    for (int mq = 0; mq < 2; ++mq)
                        oacc[mq][dt] = __builtin_amdgcn_mfma_f32_16x16x16bf16_1k(pas[mk][mq], bvs, oacc[mq][dt], 0, 0, 0);
                }
                #pragma unroll
                for (int mq = 0; mq < 2; ++mq)
                    liacc[mq] = __builtin_amdgcn_mfma_f32_16x16x16bf16_1k(pas[mk][mq], ones_s, liacc[mq], 0, 0, 0);
            }
        }

        asm volatile("s_barrier" ::: "memory");   // compute done; buf reusable
    }

    // -------- in-LDS combine: group 1 -> its freed staging area -------------
    float* pO = reinterpret_cast<float*>(&SM[1][0][0][0]);   // 32 KB
    float* pl = reinterpret_cast<float*>(&SM[0][0][0][0]);   // 512 B used
    if (g == 1) {
        #pragma unroll
        for (int mq = 0; mq < 2; ++mq)
            #pragma unroll
            for (int r = 0; r < 4; ++r) {
                int row = mq * 16 + quad * 4 + r;            // 0..31
                int sw  = ((row >> 2) & 3) << 3;
                #pragma unroll
                for (int dt = 0; dt < 4; ++dt)
                    pO[(wh * 32 + row) * 64 + ((dt * 16 + l15) ^ sw)] = oacc[mq][dt][r];
                if (l15 == 0) pl[wh * 32 + row] = liacc[mq][r];
            }
    }
    asm volatile("s_waitcnt lgkmcnt(0)" ::: "memory");
    asm volatile("s_barrier" ::: "memory");
    if (g == 0) {
        #pragma unroll
        for (int mq = 0; mq < 2; ++mq)
            #pragma unroll
            for (int r = 0; r < 4; ++r) {
                int row = mq * 16 + quad * 4 + r;            // 0..31
                int sw  = ((row >> 2) & 3) << 3;
                float l = liacc[mq][r] + pl[wh * 32 + row];
                float inv = 1.0f / l;
                #pragma unroll
                for (int dt = 0; dt < 4; ++dt) {
                    float o = oacc[mq][dt][r] + pO[(wh * 32 + row) * 64 + ((dt * 16 + l15) ^ sw)];
                    g_om[(size_t)(q0 + row) * HID + head * 64 + dt * 16 + l15] = (bf16_t)(o * inv);
                }
            }
    }
}

// ---------------------------------------------------------------------------
// Launch: 4 dispatches.
// ---------------------------------------------------------------------------
extern "C" void kernel_launch(void* const* d_in, const int* in_sizes, int n_in,
                              void* d_out, int out_size, void* d_ws, size_t ws_size,
                              hipStream_t stream) {
    const float* x    = (const float*)d_in[0];
    const float* qpW  = (const float*)d_in[1];
    const float* kpW  = (const float*)d_in[2];
    const float* vpW  = (const float*)d_in[3];
    const float* opW  = (const float*)d_in[4];
    const void*  invf = d_in[5];
    float* out = (float*)d_out;

    prep_kernel<<<2304, 256, 0, stream>>>(x, qpW, kpW, vpW, invf);     // rope+x+qkv-w
    gemm_fused_kernel<<<1792, 256, 0, stream>>>(nullptr, 0, opW);      // QKV + W_o^T
    flash_part_kernel<<<512, 512, 0, stream>>>();                      // 8kv x 64slot
    gemm_fused_kernel<<<512, 256, 0, stream>>>(out, 1, nullptr);       // O
}